// Round 1
// baseline (2438.344 us; speedup 1.0000x reference)
//
#include <hip/hip_runtime.h>

#define BATCH 16
#define C_IN 128
#define C_OUT 128
#define KS 3
#define HH 128
#define WWID 128
#define HDIM 512
#define OH 126
#define OW 126
#define W_SIZE (C_OUT * C_IN * KS * KS) /* 147456 */

// ---------------- Kernel 1: per-sample conv weights: w[b][n] = h[b] . Wh[n] + bh[n]
// One wave per row n of Wh. Row = 512 floats = 2KB, loaded as 2x float4 per lane.
__global__ __launch_bounds__(256) void gen_w_kernel(
    const float* __restrict__ h, const float* __restrict__ Wh,
    const float* __restrict__ bh, float* __restrict__ wbuf)
{
    const int lane = threadIdx.x & 63;
    const int wave = threadIdx.x >> 6;
    const int stride = gridDim.x * 4;
    for (int row = blockIdx.x * 4 + wave; row < W_SIZE; row += stride) {
        const float4* wr = (const float4*)(Wh + (size_t)row * HDIM);
        float4 a0 = wr[lane * 2];
        float4 a1 = wr[lane * 2 + 1];
        float bias = bh[row];
        #pragma unroll
        for (int b = 0; b < BATCH; ++b) {
            const float4* hb = (const float4*)(h + b * HDIM);
            float4 h0 = hb[lane * 2];
            float4 h1 = hb[lane * 2 + 1];
            float p = a0.x * h0.x + a0.y * h0.y + a0.z * h0.z + a0.w * h0.w
                    + a1.x * h1.x + a1.y * h1.y + a1.z * h1.z + a1.w * h1.w;
            #pragma unroll
            for (int m = 1; m < 64; m <<= 1) p += __shfl_xor(p, m, 64);
            if (lane == 0) wbuf[(size_t)b * W_SIZE + row] = p + bias;
        }
    }
}

// ---------------- Kernel 2: per-sample bias: bbuf[b][co] = h[b] . Wb[co] + bb[co]
__global__ __launch_bounds__(256) void gen_b_kernel(
    const float* __restrict__ h, const float* __restrict__ Wb,
    const float* __restrict__ bb, float* __restrict__ bbuf)
{
    const int idx = blockIdx.x * 256 + threadIdx.x;   // 0..2047
    const int co = idx >> 4;
    const int b  = idx & 15;
    const float* hb = h + b * HDIM;
    const float* wr = Wb + co * HDIM;
    float acc = 0.f;
    for (int k = 0; k < HDIM; k += 4) {
        acc += hb[k] * wr[k] + hb[k + 1] * wr[k + 1]
             + hb[k + 2] * wr[k + 2] + hb[k + 3] * wr[k + 3];
    }
    bbuf[b * C_OUT + co] = acc + bb[co];
}

// ---------------- Kernel 3: direct conv, VALID.
// Block: 256 threads = 16x16 output tile, 8 output channels per block.
// Loop over ci: stage 18x18 input tile in LDS; weights are block-uniform ->
// compiler scalarizes loads into SGPRs; 72 fp32 FMA per thread per ci.
__global__ __launch_bounds__(256) void conv_kernel(
    const float* __restrict__ x, const float* __restrict__ wbuf,
    const float* __restrict__ bbuf, float* __restrict__ out)
{
    __shared__ float xt[18 * 18];
    const int tid = threadIdx.x;
    const int tx = tid & 15;
    const int ty = tid >> 4;
    const int z  = blockIdx.z;           // 0..255
    const int b  = z >> 4;
    const int co0 = (z & 15) * 8;
    const int ix0 = blockIdx.x * 16;
    const int iy0 = blockIdx.y * 16;

    float acc[8];
    #pragma unroll
    for (int i = 0; i < 8; ++i) acc[i] = 0.f;

    const float* xb = x + (size_t)b * C_IN * HH * WWID;
    const float* wb = wbuf + (size_t)b * W_SIZE + (size_t)co0 * C_IN * 9;

    for (int ci = 0; ci < C_IN; ++ci) {
        __syncthreads();
        const float* xc = xb + ci * HH * WWID;
        for (int t = tid; t < 18 * 18; t += 256) {
            int r = t / 18;
            int c = t - r * 18;
            int gy = iy0 + r;
            int gx = ix0 + c;
            xt[t] = (gy < HH && gx < WWID) ? xc[gy * WWID + gx] : 0.f;
        }
        __syncthreads();

        float xr[9];
        #pragma unroll
        for (int ky = 0; ky < 3; ++ky)
            #pragma unroll
            for (int kx = 0; kx < 3; ++kx)
                xr[ky * 3 + kx] = xt[(ty + ky) * 18 + tx + kx];

        const float* wc = wb + ci * 9;
        #pragma unroll
        for (int c8 = 0; c8 < 8; ++c8) {
            const float* w = wc + (size_t)c8 * C_IN * 9;
            acc[c8] += xr[0] * w[0] + xr[1] * w[1] + xr[2] * w[2]
                     + xr[3] * w[3] + xr[4] * w[4] + xr[5] * w[5]
                     + xr[6] * w[6] + xr[7] * w[7] + xr[8] * w[8];
        }
    }

    const int oy = iy0 + ty;
    const int ox = ix0 + tx;
    if (oy < OH && ox < OW) {
        #pragma unroll
        for (int c8 = 0; c8 < 8; ++c8) {
            out[(((size_t)b * C_OUT + co0 + c8) * OH + oy) * OW + ox] =
                acc[c8] + bbuf[b * C_OUT + co0 + c8];
        }
    }
}

extern "C" void kernel_launch(void* const* d_in, const int* in_sizes, int n_in,
                              void* d_out, int out_size, void* d_ws, size_t ws_size,
                              hipStream_t stream) {
    const float* x  = (const float*)d_in[0];
    const float* h  = (const float*)d_in[1];
    const float* Wh = (const float*)d_in[2];
    const float* bh = (const float*)d_in[3];
    const float* Wb = (const float*)d_in[4];
    const float* bb = (const float*)d_in[5];
    float* out  = (float*)d_out;
    float* wbuf = (float*)d_ws;                       // B * W_SIZE floats (9.4 MB)
    float* bbuf = wbuf + (size_t)BATCH * W_SIZE;      // B * C_OUT floats

    gen_w_kernel<<<1152, 256, 0, stream>>>(h, Wh, bh, wbuf);
    gen_b_kernel<<<8, 256, 0, stream>>>(h, Wb, bb, bbuf);
    conv_kernel<<<dim3(8, 8, 256), 256, 0, stream>>>(x, wbuf, bbuf, out);
}

// Round 2
// 733.380 us; speedup vs baseline: 3.3248x; 3.3248x over previous
//
#include <hip/hip_runtime.h>

#define BATCH 16
#define C_IN 128
#define C_OUT 128
#define HH 128
#define WW 128
#define HDIM 512
#define OH 126
#define OW 126
#define NTAP 9
#define WPB (NTAP * C_OUT * C_IN)          /* 147456 w-elements per batch */
#define XT_ELEMS ((size_t)BATCH * HH * WW * C_IN)

typedef __attribute__((ext_vector_type(8))) short short8;
typedef __attribute__((ext_vector_type(4))) float floatx4;
typedef __attribute__((ext_vector_type(16))) float floatx16;

__device__ __forceinline__ unsigned short f2bf(float f) {
    union { float f; unsigned u; } v; v.f = f;
    unsigned r = v.u + 0x7FFF + ((v.u >> 16) & 1);   // RNE
    return (unsigned short)(r >> 16);
}

// ---------------- Kernel 0: x (b,ci,y,x) fp32 -> xT (b, y*128+x, ci) bf16
__global__ __launch_bounds__(256) void xpose_kernel(
    const float* __restrict__ x, unsigned short* __restrict__ xT)
{
    __shared__ float tile[64][65];
    const int b   = blockIdx.z;
    const int ci0 = blockIdx.y * 64;
    const int p0  = blockIdx.x * 64;
    const int lp  = threadIdx.x & 63;
    const int lg  = threadIdx.x >> 6;
    const float* xb = x + ((size_t)b * C_IN + ci0) * (HH * WW) + p0;
    #pragma unroll
    for (int i = 0; i < 16; ++i) {
        int ci = lg * 16 + i;
        tile[ci][lp] = xb[(size_t)ci * (HH * WW) + lp];
    }
    __syncthreads();
    unsigned short* ob = xT + ((size_t)b * (HH * WW) + p0) * C_IN + ci0;
    #pragma unroll
    for (int i = 0; i < 16; ++i) {
        int p = lg * 16 + i;
        ob[(size_t)p * C_IN + lp] = f2bf(tile[lp][p]);
    }
}

// ---------------- Kernel 1: hypernet weights via MFMA.
// C[16 batches][147456] = h(16x512) @ Wh^T, output layout wbuf[b][tap][co][ci] bf16.
// N-tile order follows the OUTPUT layout: n' = tap*16384 + co*128 + ci.
__global__ __launch_bounds__(256) void gen_w_kernel(
    const float* __restrict__ h, const float* __restrict__ Wh,
    const float* __restrict__ bh, unsigned short* __restrict__ wbuf)
{
    __shared__ unsigned short hl[16 * 520];   // padded stride: bank-conflict-free A reads
    const int tid = threadIdx.x;
    for (int i = tid; i < 16 * 512; i += 256) {
        int m = i >> 9, k = i & 511;
        hl[m * 520 + k] = f2bf(h[i]);
    }
    __syncthreads();
    const int wave = tid >> 6, lane = tid & 63;
    const int m  = lane & 15;     // batch row
    const int kg = lane >> 4;     // k-group 0..3

    short8 afr[16];               // all A fragments for K=512, loaded once
    #pragma unroll
    for (int kk = 0; kk < 16; ++kk)
        afr[kk] = *(const short8*)&hl[m * 520 + kk * 32 + kg * 8];

    const int wtile0 = (blockIdx.x * 4 + wave) * 3;
    for (int t = 0; t < 3; ++t) {
        const int n0  = (wtile0 + t) * 16;
        const int npr = n0 + (lane & 15);            // this lane's n' (col index)
        const int tap = npr >> 14;
        const int co  = (npr >> 7) & 127;
        const int ci  = npr & 127;
        const size_t whrow = (size_t)co * (C_IN * NTAP) + (size_t)ci * NTAP + tap;
        const float* wr = Wh + whrow * HDIM + kg * 8;

        floatx4 acc = {0.f, 0.f, 0.f, 0.f};
        #pragma unroll
        for (int kk = 0; kk < 16; ++kk) {
            float4 b0 = *(const float4*)(wr + kk * 32);
            float4 b1 = *(const float4*)(wr + kk * 32 + 4);
            short8 bfr;
            bfr[0] = (short)f2bf(b0.x); bfr[1] = (short)f2bf(b0.y);
            bfr[2] = (short)f2bf(b0.z); bfr[3] = (short)f2bf(b0.w);
            bfr[4] = (short)f2bf(b1.x); bfr[5] = (short)f2bf(b1.y);
            bfr[6] = (short)f2bf(b1.z); bfr[7] = (short)f2bf(b1.w);
            acc = __builtin_amdgcn_mfma_f32_16x16x32_bf16(afr[kk], bfr, acc, 0, 0, 0);
        }
        const float bias = bh[whrow];
        #pragma unroll
        for (int r = 0; r < 4; ++r) {
            int bt = kg * 4 + r;                     // batch = row = (lane>>4)*4 + reg
            wbuf[(size_t)bt * WPB + npr] = f2bf(acc[r] + bias);
        }
    }
}

// ---------------- Kernel 2: per-sample bias (fp32 exact)
__global__ __launch_bounds__(256) void gen_b_kernel(
    const float* __restrict__ h, const float* __restrict__ Wb,
    const float* __restrict__ bb, float* __restrict__ bbuf)
{
    const int idx = blockIdx.x * 256 + threadIdx.x;   // 0..2047
    const int co = idx >> 4;
    const int b  = idx & 15;
    const float* hb = h + b * HDIM;
    const float* wr = Wb + co * HDIM;
    float acc = 0.f;
    for (int k = 0; k < HDIM; k += 4)
        acc += hb[k] * wr[k] + hb[k+1] * wr[k+1] + hb[k+2] * wr[k+2] + hb[k+3] * wr[k+3];
    bbuf[b * C_OUT + co] = acc + bb[co];
}

// ---------------- Kernel 3: conv as implicit GEMM, 32x32x16 bf16 MFMA.
// Block: batch b, out rows y0..y0+1, all 128 cols, all 128 co. 4 waves:
// wave = (row, col-half); per wave 4 M-tiles x 2 N-tiles of 32x32.
__global__ __launch_bounds__(256, 2) void conv_kernel(
    const unsigned short* __restrict__ xT, const unsigned short* __restrict__ wbuf,
    const float* __restrict__ bbuf, float* __restrict__ out)
{
    __shared__ unsigned short patch[1024 * 8];   // 1024 16B-slots, swizzled
    __shared__ float biasl[C_OUT];
    const int tid = threadIdx.x, lane = tid & 63, wave = tid >> 6;
    const int y0 = blockIdx.x * 2;
    const int b  = blockIdx.y;
    if (tid < C_OUT) biasl[tid] = bbuf[b * C_OUT + tid];

    const int rw = wave >> 1;       // wave's output row within block (0/1)
    const int ch = wave & 1;        // wave's column half (0/1)
    const int l31 = lane & 31, lh = lane >> 5;

    floatx16 acc[4][2];
    #pragma unroll
    for (int mt = 0; mt < 4; ++mt)
        #pragma unroll
        for (int cg = 0; cg < 2; ++cg)
            acc[mt][cg] = (floatx16)(0.f);

    const unsigned short* xTb = xT + (size_t)b * (HH * WW) * C_IN;
    const unsigned short* wb  = wbuf + (size_t)b * WPB;

    for (int cc = 0; cc < 8; ++cc) {
        const int ci0 = cc * 16;
        __syncthreads();                      // prev chunk's reads done
        #pragma unroll
        for (int i = 0; i < 4; ++i) {
            const int s0 = wave * 256 + i * 64;      // wave-uniform slot base
            const int s  = s0 + lane;
            const int r  = s >> 8;
            const int c  = (s >> 1) & 127;
            const int hh = (s & 1) ^ ((c >> 2) & 1); // ci-half, swizzled
            const unsigned short* g =
                xTb + ((size_t)(y0 + r) * WW + c) * C_IN + ci0 + hh * 8;
            __builtin_amdgcn_global_load_lds(
                (const __attribute__((address_space(1))) void*)g,
                (__attribute__((address_space(3))) void*)(patch + s0 * 8),
                16, 0, 0);
        }
        __syncthreads();                      // staging visible

        #pragma unroll
        for (int tap = 0; tap < 9; ++tap) {
            const int ky = tap / 3, kx = tap % 3;
            short8 af[4];
            const unsigned short* wt = wb + (size_t)tap * C_OUT * C_IN + ci0 + lh * 8;
            #pragma unroll
            for (int mt = 0; mt < 4; ++mt)
                af[mt] = *(const short8*)(wt + (size_t)(mt * 32 + l31) * C_IN);
            short8 bf[2];
            const int r = rw + ky;
            #pragma unroll
            for (int cg = 0; cg < 2; ++cg) {
                int c = ch * 64 + cg * 32 + l31 + kx;
                c = min(c, 127);
                const int slot = r * 256 + c * 2 + (lh ^ ((c >> 2) & 1));
                bf[cg] = *(const short8*)(patch + slot * 8);
            }
            #pragma unroll
            for (int mt = 0; mt < 4; ++mt)
                #pragma unroll
                for (int cg = 0; cg < 2; ++cg)
                    acc[mt][cg] = __builtin_amdgcn_mfma_f32_32x32x16_bf16(
                        af[mt], bf[cg], acc[mt][cg], 0, 0, 0);
        }
    }

    // Epilogue: C/D 32x32 layout: col=lane&31, row=(reg&3)+8*(reg>>2)+4*(lane>>5)
    const int oy = y0 + rw;
    const int ox = ch * 64 + l31;     // cg adds 32
    #pragma unroll
    for (int mt = 0; mt < 4; ++mt) {
        #pragma unroll
        for (int cg = 0; cg < 2; ++cg) {
            const int oxc = ox + cg * 32;
            if (oxc < OW) {
                #pragma unroll
                for (int rg = 0; rg < 16; ++rg) {
                    const int row = (rg & 3) + 8 * (rg >> 2) + 4 * lh;
                    const int co  = mt * 32 + row;
                    out[(((size_t)b * C_OUT + co) * OH + oy) * OW + oxc] =
                        acc[mt][cg][rg] + biasl[co];
                }
            }
        }
    }
}

extern "C" void kernel_launch(void* const* d_in, const int* in_sizes, int n_in,
                              void* d_out, int out_size, void* d_ws, size_t ws_size,
                              hipStream_t stream) {
    const float* x  = (const float*)d_in[0];
    const float* h  = (const float*)d_in[1];
    const float* Wh = (const float*)d_in[2];
    const float* bh = (const float*)d_in[3];
    const float* Wb = (const float*)d_in[4];
    const float* bb = (const float*)d_in[5];
    float* out = (float*)d_out;

    unsigned short* xT   = (unsigned short*)d_ws;                   // 67108864 B
    unsigned short* wbuf = xT + XT_ELEMS;                           // 4718592 B
    float*          bbuf = (float*)(wbuf + (size_t)BATCH * WPB);    // 8192 B

    xpose_kernel<<<dim3(256, 2, BATCH), 256, 0, stream>>>(x, xT);
    gen_w_kernel<<<768, 256, 0, stream>>>(h, Wh, bh, wbuf);
    gen_b_kernel<<<8, 256, 0, stream>>>(h, Wb, bb, bbuf);
    conv_kernel<<<dim3(63, BATCH), 256, 0, stream>>>(xT, wbuf, bbuf, out);
}